// Round 18
// baseline (213.192 us; speedup 1.0000x reference)
//
#include <hip/hip_runtime.h>
#include <hip/hip_bf16.h>
#include <stdint.h>

#define D_MODEL 1024
#define SEQ 2048
#define BATCH 4
#define NHEADS 16
#define ROWS (BATCH*SEQ)   // 8192

// Q pre-scale: (1/sqrt(64)) * log2(e) so attention softmax can use v_exp_f32 (2^x)
#define QKSCALE 0.18033688011f

typedef __attribute__((ext_vector_type(4))) float f32x4;
typedef __attribute__((ext_vector_type(8))) short short8;
typedef __attribute__((ext_vector_type(4))) unsigned int uint4v;

#if __has_builtin(__builtin_amdgcn_exp2f)
#define EXP2(x) __builtin_amdgcn_exp2f(x)
#else
#define EXP2(x) exp2f(x)
#endif

__device__ __forceinline__ unsigned short f2bf(float f) {
    unsigned int x = __builtin_bit_cast(unsigned int, f);
    x += 0x7fffu + ((x >> 16) & 1u);   // RNE
    return (unsigned short)(x >> 16);
}

// v_cvt_pk_bf16_f32: lo = bf16(a), hi = bf16(b)  (RNE)
__device__ __forceinline__ unsigned int cvtpk(float a, float b) {
    unsigned int r;
    asm("v_cvt_pk_bf16_f32 %0, %1, %2" : "=v"(r) : "v"(a), "v"(b));
    return r;
}

__device__ __forceinline__ void gload16(const unsigned short* src, unsigned short* dst) {
    __builtin_amdgcn_global_load_lds(
        (const __attribute__((address_space(1))) void*)src,
        (__attribute__((address_space(3))) void*)dst, 16, 0, 0);
}

// ---------- weight transpose + f32->bf16 into BLOCKED-SWIZZLED panels --------
__global__ __launch_bounds__(256) void wtrans_kernel(const float* __restrict__ w0,
                                                     const float* __restrict__ w1,
                                                     const float* __restrict__ w2,
                                                     const float* __restrict__ w3,
                                                     unsigned short* __restrict__ wt0,
                                                     unsigned short* __restrict__ wt1,
                                                     unsigned short* __restrict__ wt2,
                                                     unsigned short* __restrict__ wt3) {
    const int z = blockIdx.z;
    const float* w = (z == 0) ? w0 : (z == 1) ? w1 : (z == 2) ? w2 : w3;
    unsigned short* wt = (z == 0) ? wt0 : (z == 1) ? wt1 : (z == 2) ? wt2 : wt3;
    __shared__ float tile[32][33];    // [k_local][n_local]
    int tx = threadIdx.x & 31;
    int ty = threadIdx.x >> 5;        // 0..7
    int r0 = blockIdx.y * 32, c0 = blockIdx.x * 32;   // r = k dim, c = n dim
    #pragma unroll
    for (int i = 0; i < 4; ++i)
        tile[ty + 8*i][tx] = w[(size_t)(r0 + ty + 8*i) * D_MODEL + (c0 + tx)];
    __syncthreads();
    int t = threadIdx.x;
    if (t < 128) {
        int n_loc = t >> 2;           // 0..31
        int kc = t & 3;               // 8-wide k chunk
        int n = c0 + n_loc;
        int kbase = r0 + kc*8;
        uint4v pk;
        #pragma unroll
        for (int j = 0; j < 4; ++j)
            pk[j] = cvtpk(tile[kc*8 + 2*j][n_loc], tile[kc*8 + 2*j + 1][n_loc]);
        size_t tidx = (size_t)(n >> 7) * 16 + (kbase >> 6);
        int row = n & 127;
        int byte = (row*128 + (kbase & 63)*2) ^ ((row & 7) << 4);
        *(uint4v*)((char*)wt + tidx*16384 + byte) = pk;
    }
}

// ---------- merged Q/K/V projection GEMM (z = 0/1/2), 128x256 tile ----------
// 4 waves as 2(m)x2(n); each wave 64x128 (acc 4x8).  Single-buffered A (av[]
// regs are the 2nd buffer) + double-buffered 256-col B (two adjacent 128-col
// tile images, contiguous) = 80KB.  Two uniform barriers per K-step; half the
// blocks of the 128x128 version -> half the total barrier stalls.
// Epilogues: z=0 Q scaled [b,h,s,64]; z=1 K sigma-permuted swizzled tile
// image; z=2 V^T swizzled tile image.
__global__ __launch_bounds__(256) void qkv_gemm_kernel(
        const float* __restrict__ qin, const float* __restrict__ kin,
        const float* __restrict__ vin,
        const unsigned short* __restrict__ wqt, const unsigned short* __restrict__ wkt,
        const unsigned short* __restrict__ wvt,
        const float* __restrict__ bq, const float* __restrict__ bk,
        const float* __restrict__ bv,
        unsigned short* __restrict__ qhd, unsigned short* __restrict__ khd,
        unsigned short* __restrict__ vtd) {
    __shared__ __attribute__((aligned(16))) unsigned short Alds[128*64];
    __shared__ __attribute__((aligned(16))) unsigned short Blds[2][256*64];
    const int z = blockIdx.z;
    const float* Af = (z == 0) ? qin : (z == 1) ? kin : vin;
    const unsigned short* Bt = (z == 0) ? wqt : (z == 1) ? wkt : wvt;
    const float* bias = (z == 0) ? bq : (z == 1) ? bk : bv;
    const int m0 = blockIdx.x * 128;
    const int n0 = blockIdx.y * 256;
    const int t = threadIdx.x;
    const int lane = t & 63;
    const int w = t >> 6;
    const int wm = w >> 1, wn = w & 1;        // 2x2 wave grid: 64(m) x 128(n)
    const int l15 = lane & 15, lg = lane >> 4;
    // two adjacent 128-col panels, contiguous: panel p at tbase + p*16*8192
    const unsigned short* tbase = Bt + (size_t)(n0 >> 7) * 16 * 8192;

    f32x4 acc[4][8];
    #pragma unroll
    for (int i = 0; i < 4; ++i)
        #pragma unroll
        for (int j = 0; j < 8; ++j) acc[i][j] = (f32x4)(0.0f);

    // ---- prologue: stage A(0) (reg convert), issue B(0) (both panels) ----
    #pragma unroll
    for (int i = 0; i < 8; ++i) {
        int idx = t + i*256;
        int row = idx >> 4, c4 = idx & 15;
        f32x4 v = *(const f32x4*)(Af + (size_t)(m0+row)*D_MODEL + c4*4);
        unsigned long long pk = (unsigned long long)cvtpk(v[0], v[1])
                              | ((unsigned long long)cvtpk(v[2], v[3]) << 32);
        int byte = (row*128 + c4*8) ^ ((row & 7) << 4);
        *(unsigned long long*)((char*)Alds + byte) = pk;
    }
    #pragma unroll
    for (int p = 0; p < 2; ++p)
        #pragma unroll
        for (int i = 0; i < 4; ++i)
            gload16(tbase + (size_t)p*16*8192 + t*8 + i*2048,
                    Blds[0] + p*8192 + t*8 + i*2048);
    __syncthreads();

    #pragma unroll 2
    for (int kt = 0; kt < 16; ++kt) {
        const int cur = kt & 1, nxt = cur ^ 1;
        f32x4 av[8];
        if (kt < 15) {
            const int k0n = (kt + 1) * 64;
            #pragma unroll
            for (int i = 0; i < 8; ++i) {
                int idx = t + i*256;
                int row = idx >> 4, c4 = idx & 15;
                av[i] = *(const f32x4*)(Af + (size_t)(m0+row)*D_MODEL + k0n + c4*4);
            }
            #pragma unroll
            for (int p = 0; p < 2; ++p) {
                const unsigned short* tsrc = tbase + (size_t)p*16*8192 + (size_t)(kt + 1) * 8192;
                #pragma unroll
                for (int i = 0; i < 4; ++i)
                    gload16(tsrc + t*8 + i*2048, Blds[nxt] + p*8192 + t*8 + i*2048);
            }
        }

        #pragma unroll
        for (int kk = 0; kk < 2; ++kk) {
            short8 af[4];
            #pragma unroll
            for (int mi = 0; mi < 4; ++mi) {
                int row = wm*64 + mi*16 + l15;
                int byte = (row*128 + kk*64 + lg*16) ^ ((row & 7) << 4);
                af[mi] = *(const short8*)((const char*)Alds + byte);
            }
            #pragma unroll
            for (int ni = 0; ni < 8; ++ni) {
                int row = wn*128 + ni*16 + l15;        // 0..255; row*128 spans panels
                int byte = (row*128 + kk*64 + lg*16) ^ ((row & 7) << 4);
                short8 bf = *(const short8*)((const char*)Blds[cur] + byte);
                #pragma unroll
                for (int mi = 0; mi < 4; ++mi)
                    acc[mi][ni] = __builtin_amdgcn_mfma_f32_16x16x32_bf16(
                        af[mi], bf, acc[mi][ni], 0, 0, 0);
            }
        }
        __syncthreads();                       // all waves done reading Alds
        if (kt < 15) {
            #pragma unroll
            for (int i = 0; i < 8; ++i) {
                int idx = t + i*256;
                int row = idx >> 4, c4 = idx & 15;
                unsigned long long pk = (unsigned long long)cvtpk(av[i][0], av[i][1])
                                      | ((unsigned long long)cvtpk(av[i][2], av[i][3]) << 32);
                int byte = (row*128 + c4*8) ^ ((row & 7) << 4);
                *(unsigned long long*)((char*)Alds + byte) = pk;
            }
            __syncthreads();                   // A(kt+1) visible to all waves
        }
    }

    // epilogue: C/D layout col = lane&15, row = (lane>>4)*4 + reg
    #pragma unroll
    for (int mi = 0; mi < 4; ++mi)
        #pragma unroll
        for (int ni = 0; ni < 8; ++ni) {
            int col = n0 + wn*128 + ni*16 + l15;
            float bv_ = bias[col];
            int h = col >> 6, d = col & 63;
            if (z == 0) {
                // Q: bf16 [b,h,s,64], scaled
                #pragma unroll
                for (int r = 0; r < 4; ++r) {
                    int row = m0 + wm*64 + mi*16 + lg*4 + r;
                    int bb = row >> 11, s = row & 2047;
                    float vv = (acc[mi][ni][r] + bv_) * QKSCALE;
                    qhd[(((size_t)(bb*NHEADS + h)*SEQ + s) << 6) + d] = f2bf(vv);
                }
            } else if (z == 1) {
                // K tile image: row=sigma(kv), col=d
                #pragma unroll
                for (int r = 0; r < 4; ++r) {
                    int row = m0 + wm*64 + mi*16 + lg*4 + r;
                    int bb = row >> 11, s = row & 2047;
                    int ti = s >> 6, kvl = s & 63;
                    int ph = (kvl & 0x23) | ((kvl & 4) << 2) | ((kvl & 0x18) >> 1);
                    int byte = (ph*128 + d*2) ^ ((ph & 7) << 4);
                    *(unsigned short*)((char*)khd
                        + ((size_t)(bb*NHEADS + h)*32 + ti)*8192 + byte)
                        = f2bf(acc[mi][ni][r] + bv_);
                }
            } else {
                // V^T tile image: row=d, col=kv; 4 consecutive kv = 8B store
                int row0 = m0 + wm*64 + mi*16 + lg*4;
                int bb = row0 >> 11, s0 = row0 & 2047;
                int ti = s0 >> 6, kvl0 = s0 & 63;
                unsigned long long pk = 0;
                #pragma unroll
                for (int r = 0; r < 4; ++r)
                    pk |= (unsigned long long)f2bf(acc[mi][ni][r] + bv_) << (16*r);
                int byte = (d*128 + kvl0*2) ^ ((d & 7) << 4);
                *(unsigned long long*)((char*)vtd
                    + ((size_t)(bb*NHEADS + h)*32 + ti)*8192 + byte) = pk;
            }
        }
}

// ---------- final GEMM: d_out[8192x1024] f32 = xat * wot^T + bo, 128x256 ----
__global__ __launch_bounds__(256) void out_gemm_kernel(const unsigned short* __restrict__ Ab,
                                                       const unsigned short* __restrict__ Bt,
                                                       const float* __restrict__ bias,
                                                       float* __restrict__ Out) {
    __shared__ __attribute__((aligned(16))) unsigned short Alds[128*64];
    __shared__ __attribute__((aligned(16))) unsigned short Blds[2][256*64];
    const int m0 = blockIdx.x * 128;
    const int n0 = blockIdx.y * 256;
    const int t = threadIdx.x;
    const int lane = t & 63;
    const int w = t >> 6;
    const int wm = w >> 1, wn = w & 1;
    const int l15 = lane & 15, lg = lane >> 4;
    const unsigned short* tbase = Bt + (size_t)(n0 >> 7) * 16 * 8192;

    f32x4 acc[4][8];
    #pragma unroll
    for (int i = 0; i < 4; ++i)
        #pragma unroll
        for (int j = 0; j < 8; ++j) acc[i][j] = (f32x4)(0.0f);

    // prologue: stage A(0) (reg path), issue B(0) both panels
    #pragma unroll
    for (int i = 0; i < 4; ++i) {
        int idx = t + i*256;
        int row = idx >> 3, c8 = idx & 7;
        short8 v = *(const short8*)(Ab + (size_t)(m0+row)*D_MODEL + c8*8);
        int byte = (row*128 + c8*16) ^ ((row & 7) << 4);
        *(short8*)((char*)Alds + byte) = v;
    }
    #pragma unroll
    for (int p = 0; p < 2; ++p)
        #pragma unroll
        for (int i = 0; i < 4; ++i)
            gload16(tbase + (size_t)p*16*8192 + t*8 + i*2048,
                    Blds[0] + p*8192 + t*8 + i*2048);
    __syncthreads();

    #pragma unroll 2
    for (int kt = 0; kt < 16; ++kt) {
        const int cur = kt & 1, nxt = cur ^ 1;
        short8 av8[4];
        if (kt < 15) {
            const int k0n = (kt + 1) * 64;
            #pragma unroll
            for (int i = 0; i < 4; ++i) {
                int idx = t + i*256;
                int row = idx >> 3, c8 = idx & 7;
                av8[i] = *(const short8*)(Ab + (size_t)(m0+row)*D_MODEL + k0n + c8*8);
            }
            #pragma unroll
            for (int p = 0; p < 2; ++p) {
                const unsigned short* tsrc = tbase + (size_t)p*16*8192 + (size_t)(kt + 1) * 8192;
                #pragma unroll
                for (int i = 0; i < 4; ++i)
                    gload16(tsrc + t*8 + i*2048, Blds[nxt] + p*8192 + t*8 + i*2048);
            }
        }

        #pragma unroll
        for (int kk = 0; kk < 2; ++kk) {
            short8 af[4];
            #pragma unroll
            for (int mi = 0; mi < 4; ++mi) {
                int row = wm*64 + mi*16 + l15;
                int byte = (row*128 + kk*64 + lg*16) ^ ((row & 7) << 4);
                af[mi] = *(const short8*)((const char*)Alds + byte);
            }
            #pragma unroll
            for (int ni = 0; ni < 8; ++ni) {
                int row = wn*128 + ni*16 + l15;
                int byte = (row*128 + kk*64 + lg*16) ^ ((row & 7) << 4);
                short8 bf = *(const short8*)((const char*)Blds[cur] + byte);
                #pragma unroll
                for (int mi = 0; mi < 4; ++mi)
                    acc[mi][ni] = __builtin_amdgcn_mfma_f32_16x16x32_bf16(
                        af[mi], bf, acc[mi][ni], 0, 0, 0);
            }
        }
        __syncthreads();
        if (kt < 15) {
            #pragma unroll
            for (int i = 0; i < 4; ++i) {
                int idx = t + i*256;
                int row = idx >> 3, c8 = idx & 7;
                int byte = (row*128 + c8*16) ^ ((row & 7) << 4);
                *(short8*)((char*)Alds + byte) = av8[i];
            }
            __syncthreads();
        }
    }

    #pragma unroll
    for (int mi = 0; mi < 4; ++mi)
        #pragma unroll
        for (int ni = 0; ni < 8; ++ni) {
            int col = n0 + wn*128 + ni*16 + l15;
            float bv_ = bias[col];
            #pragma unroll
            for (int r = 0; r < 4; ++r) {
                int row = m0 + wm*64 + mi*16 + lg*4 + r;
                Out[(size_t)row*D_MODEL + col] = acc[mi][ni][r] + bv_;
            }
        }
}

// ---------- flash attention: swapped QK^T, in-register P, 32 q-rows/wave ------
// (R15/R16 best version.)  4 waves x 32 q-rows = 128 q rows per block;
// KVBLK=64; double-buffered LDS; K/V arrive as pre-swizzled tile images ->
// staging is pure global_load_lds.  Softmax: m FIXED at tile-0's row max;
// lsum per-lane VALU partial, reduced once in the epilogue.
// Grid: flat 1024, bh = (idx&7)*8 + xcd so one head's 16 q-blocks share an XCD.
__global__ __launch_bounds__(256, 4) void attn_kernel(const unsigned short* __restrict__ qh,
                                                      const unsigned short* __restrict__ kimg_all,
                                                      const unsigned short* __restrict__ vimg_all,
                                                      unsigned short* __restrict__ xout) {
    __shared__ __attribute__((aligned(16))) unsigned short Klds[2][64*64];
    __shared__ __attribute__((aligned(16))) unsigned short Vtl[2][64*64];

    const int bid = blockIdx.x;            // 0..1023
    const int xcd = bid & 7, idx = bid >> 3;
    const int qb = idx >> 3;               // 0..15 (128 q rows each)
    const int bh = ((idx & 7) << 3) | xcd; // 0..63; fixed bh -> fixed xcd
    const int t = threadIdx.x;             // 0..255
    const int lane = t & 63;
    const int w = t >> 6;                  // 0..3
    const int l15 = lane & 15, lg = lane >> 4;

    const unsigned short* qbase = qh + (size_t)bh * SEQ * 64;
    const unsigned short* kimg = kimg_all + (size_t)bh * SEQ * 64;
    const unsigned short* vimg = vimg_all + (size_t)bh * SEQ * 64;

    // Q fragments hoisted: wave w owns q rows qb*128 + w*32 + l*16 + l15
    short8 qf[2][2];
    #pragma unroll
    for (int l = 0; l < 2; ++l) {
        int qrow = qb*128 + w*32 + l*16 + l15;
        qf[l][0] = *(const short8*)(qbase + (size_t)qrow*64 + lg*8);
        qf[l][1] = *(const short8*)(qbase + (size_t)qrow*64 + 32 + lg*8);
    }

    // hoisted fragment read offsets (same formula for K and Vt)
    int fb[4][2];
    #pragma unroll
    for (int nb = 0; nb < 4; ++nb) {
        int rr = nb*16 + l15;
        int sw = (rr & 7) << 4;
        fb[nb][0] = (rr*128 + lg*16) ^ sw;
        fb[nb][1] = (rr*128 + 64 + lg*16) ^ sw;
    }

    float m[2] = {-1e30f, -1e30f};   // fixed after tile 0 (per-lane, q = l15)
    float lsum[2] = {0.f, 0.f};      // PER-LANE partial (16-kv slice), q = l15
    f32x4 o[2][4];                   // o[l][nb][r]: q = l*16+lg*4+r, d = nb*16+l15
    #pragma unroll
    for (int l = 0; l < 2; ++l)
        #pragma unroll
        for (int nb = 0; nb < 4; ++nb) o[l][nb] = (f32x4)(0.0f);

    // prologue: stage tile 0 into buffer 0 (pure async DMA)
    #pragma unroll
    for (int i = 0; i < 2; ++i) {
        gload16(kimg + t*8 + i*2048, Klds[0] + t*8 + i*2048);
        gload16(vimg + t*8 + i*2048, Vtl[0] + t*8 + i*2048);
    }
    __syncthreads();

    const unsigned short* kp = kimg + 4096 + t*8;
    const unsigned short* vp = vimg + 4096 + t*8;

    const int NT = SEQ/64;
    #pragma unroll 2
    for (int ti = 0; ti < NT; ++ti) {
        const int c = ti & 1;
        // issue next-tile DMA early (latency hides under compute)
        if (ti + 1 < NT) {
            #pragma unroll
            for (int i = 0; i < 2; ++i) {
                gload16(kp + i*2048, Klds[c^1] + t*8 + i*2048);
                gload16(vp + i*2048, Vtl[c^1] + t*8 + i*2048);
            }
            kp += 4096; vp += 4096;
        }
        const char* Kc = (const char*)Klds[c];
        const char* Vc = (const char*)Vtl[c];

        // S^T = K Q^T for both q-groups, sharing K-fragment reads
        f32x4 s4[2][4];
        #pragma unroll
        for (int nb = 0; nb < 4; ++nb) {
            short8 kf0 = *(const short8*)(Kc + fb[nb][0]);
            short8 kf1 = *(const short8*)(Kc + fb[nb][1]);
            __builtin_amdgcn_s_setprio(1);
            #pragma unroll
            for (int l = 0; l < 2; ++l) {
                f32x4 s = (f32x4)(0.0f);
                s = __builtin_amdgcn_mfma_f32_16x16x32_bf16(kf0, qf[l][0], s, 0, 0, 0);
                s = __builtin_amdgcn_mfma_f32_16x16x32_bf16(kf1, qf[l][1], s, 0, 0, 0);
                s4[l][nb] = s;
            }
            __builtin_amdgcn_s_setprio(0);
        }

        // one-time: m = row max of tile 0 (uniform branch)
        if (ti == 0) {
            #pragma unroll
            for (int l = 0; l < 2; ++l) {
                float tm = s4[l][0][0];
                #pragma unroll
                for (int nb = 0; nb < 4; ++nb)
                    #pragma unroll
                    for (int r = 0; r < 4; ++r) tm = fmaxf(tm, s4[l][nb][r]);
                tm = fmaxf(tm, __shfl_xor(tm, 16));
                tm = fmaxf(tm, __shfl_xor(tm, 32));
                m[l] = tm;
            }
        }

        // softmax: p = 2^(s-m), fixed m; pack PA in-register; lsum per-lane VALU
        union U { short8 s; unsigned int u[4]; } pa[2][2];
        #pragma unroll
        for (int l = 0; l < 2; ++l) {
            float p[16];
            float ts = 0.f;
            #pragma unroll
            for (int nb = 0; nb < 4; ++nb)
                #pragma unroll
                for (int r = 0; r < 4; ++r) {
                    float pv = EXP2(s4[l][nb][r] - m[l]);
                    p[nb*4 + r] = pv;
                    ts += pv;
                }
            lsum[l] += ts;

            // pack PA fragments in-register: pa[l][kk] covers kv = kk*32+lg*8..+7
            pa[l][0].u[0] = cvtpk(p[0],  p[1]);  pa[l][0].u[1] = cvtpk(p[2],  p[3]);
            pa[l][0].u[2] = cvtpk(p[4],  p[5]);  pa[l][0].u[3] = cvtpk(p[6],  p[7]);
            pa[l][1].u[0] = cvtpk(p[8],  p[9]);  pa[l][1].u[1] = cvtpk(p[10], p[11]);
            pa[l][1].u[2] = cvtpk(p[12], p[13]); pa[l][1].u[3] = cvtpk(p[14], p[15]);
        }

        // O += P V, sharing V-fragment reads across both q-groups
        #pragma unroll
        for (int nb = 0; nb < 4; ++nb) {
            short8 vf0 = *(const short8*)(Vc + fb[nb][0]);
            short8 vf1 = *(const short8*)(Vc + fb[nb][1]);
            __builtin_amdgcn_s_setprio(1);
            o[0][nb] = __builtin_amdgcn_mfma_f32_16x16x32_bf16(pa[0][0].s, vf0, o[0][nb], 0, 0, 0);
            o[0][nb] = __builtin_amdgcn_mfma_f32_16x16x32_bf16(pa[0][1].s, vf1, o[0][nb], 0, 0, 0);
            o[1][nb] = __builtin_amdgcn_mfma_f32_16x16x32_bf16(pa[1][0].s, vf0, o[1][nb], 0, 0, 0);
            o[1][nb] = __builtin_amdgcn_mfma_f32_16x16x32_bf16(pa[1][1].s, vf1, o[1][nb], 0, 0, 0);
            __builtin_amdgcn_s_setprio(0);
        }

        __syncthreads();
    }

    // epilogue: reduce lsum partials across lg, then x[b][s][h*64+d] bf16
    const int bb = bh >> 4, h = bh & 15;
    #pragma unroll
    for (int l = 0; l < 2; ++l) {
        float lt = lsum[l];
        lt += __shfl_xor(lt, 16);
        lt += __shfl_xor(lt, 32);
        float rl[4];
        #pragma unroll
        for (int r = 0; r < 4; ++r) rl[r] = 1.0f / __shfl(lt, lg*4 + r);
        #pragma unroll
        for (int nb = 0; nb < 4; ++nb)
            #pragma unroll
            for (int r = 0; r < 4; ++r) {
                int s = qb*128 + w*32 + l*16 + lg*4 + r;
                int d = nb*16 + l15;
                xout[((size_t)(bb*SEQ + s))*D_MODEL + h*64 + d] = f2bf(o[l][nb][r] * rl[r]);
            }
    }
}

extern "C" void kernel_launch(void* const* d_in, const int* in_sizes, int n_in,
                              void* d_out, int out_size, void* d_ws, size_t ws_size,
                              hipStream_t stream) {
    (void)in_sizes; (void)n_in; (void)out_size; (void)ws_size;
    const float* q  = (const float*)d_in[0];
    const float* k  = (const float*)d_in[1];
    const float* v  = (const float*)d_in[2];
    const float* wq = (const float*)d_in[3];
    const float* bq = (const float*)d_in[4];
    const float* wk = (const float*)d_in[5];
    const float* bk = (const float*)d_in[6];
    const float* wv = (const float*)d_in[7];
    const float* bv = (const float*)d_in[8];
    const float* wo = (const float*)d_in[9];
    const float* bo = (const float*)d_in[10];

    // workspace layout (72 MB total)
    char* ws = (char*)d_ws;
    unsigned short* wqt = (unsigned short*)(ws);                    // 2 MB each
    unsigned short* wkt = (unsigned short*)(ws + (2ull << 20));
    unsigned short* wvt = (unsigned short*)(ws + (4ull << 20));
    unsigned short* wot = (unsigned short*)(ws + (6ull << 20));
    unsigned short* qhd = (unsigned short*)(ws + (8ull << 20));     // 16 MB each
    unsigned short* khd = (unsigned short*)(ws + (24ull << 20));
    unsigned short* vtd = (unsigned short*)(ws + (40ull << 20));
    unsigned short* xat = (unsigned short*)(ws + (56ull << 20));

    hipLaunchKernelGGL(wtrans_kernel, dim3(D_MODEL/32, D_MODEL/32, 4), dim3(256), 0, stream,
                       wq, wk, wv, wo, wqt, wkt, wvt, wot);

    hipLaunchKernelGGL(qkv_gemm_kernel, dim3(ROWS/128, D_MODEL/256, 3), dim3(256), 0, stream,
                       q, k, v, wqt, wkt, wvt, bq, bk, bv, qhd, khd, vtd);

    hipLaunchKernelGGL(attn_kernel, dim3(16*64), dim3(256), 0, stream,
                       qhd, khd, vtd, xat);

    hipLaunchKernelGGL(out_gemm_kernel, dim3(ROWS/128, D_MODEL/256), dim3(256), 0, stream,
                       xat, wot, bo, (float*)d_out);
}

// Round 19
// 189.257 us; speedup vs baseline: 1.1265x; 1.1265x over previous
//
#include <hip/hip_runtime.h>
#include <hip/hip_bf16.h>
#include <stdint.h>

#define D_MODEL 1024
#define SEQ 2048
#define BATCH 4
#define NHEADS 16
#define ROWS (BATCH*SEQ)   // 8192

// Q pre-scale: (1/sqrt(64)) * log2(e) so attention softmax can use v_exp_f32 (2^x)
#define QKSCALE 0.18033688011f

typedef __attribute__((ext_vector_type(4))) float f32x4;
typedef __attribute__((ext_vector_type(8))) short short8;
typedef __attribute__((ext_vector_type(4))) unsigned int uint4v;

#if __has_builtin(__builtin_amdgcn_exp2f)
#define EXP2(x) __builtin_amdgcn_exp2f(x)
#else
#define EXP2(x) exp2f(x)
#endif

__device__ __forceinline__ unsigned short f2bf(float f) {
    unsigned int x = __builtin_bit_cast(unsigned int, f);
    x += 0x7fffu + ((x >> 16) & 1u);   // RNE
    return (unsigned short)(x >> 16);
}

// v_cvt_pk_bf16_f32: lo = bf16(a), hi = bf16(b)  (RNE)
__device__ __forceinline__ unsigned int cvtpk(float a, float b) {
    unsigned int r;
    asm("v_cvt_pk_bf16_f32 %0, %1, %2" : "=v"(r) : "v"(a), "v"(b));
    return r;
}

__device__ __forceinline__ void gload16(const unsigned short* src, unsigned short* dst) {
    __builtin_amdgcn_global_load_lds(
        (const __attribute__((address_space(1))) void*)src,
        (__attribute__((address_space(3))) void*)dst, 16, 0, 0);
}

// ---------- weight transpose + f32->bf16 into BLOCKED-SWIZZLED panels --------
__global__ __launch_bounds__(256) void wtrans_kernel(const float* __restrict__ w0,
                                                     const float* __restrict__ w1,
                                                     const float* __restrict__ w2,
                                                     const float* __restrict__ w3,
                                                     unsigned short* __restrict__ wt0,
                                                     unsigned short* __restrict__ wt1,
                                                     unsigned short* __restrict__ wt2,
                                                     unsigned short* __restrict__ wt3) {
    const int z = blockIdx.z;
    const float* w = (z == 0) ? w0 : (z == 1) ? w1 : (z == 2) ? w2 : w3;
    unsigned short* wt = (z == 0) ? wt0 : (z == 1) ? wt1 : (z == 2) ? wt2 : wt3;
    __shared__ float tile[32][33];    // [k_local][n_local]
    int tx = threadIdx.x & 31;
    int ty = threadIdx.x >> 5;        // 0..7
    int r0 = blockIdx.y * 32, c0 = blockIdx.x * 32;   // r = k dim, c = n dim
    #pragma unroll
    for (int i = 0; i < 4; ++i)
        tile[ty + 8*i][tx] = w[(size_t)(r0 + ty + 8*i) * D_MODEL + (c0 + tx)];
    __syncthreads();
    int t = threadIdx.x;
    if (t < 128) {
        int n_loc = t >> 2;           // 0..31
        int kc = t & 3;               // 8-wide k chunk
        int n = c0 + n_loc;
        int kbase = r0 + kc*8;
        uint4v pk;
        #pragma unroll
        for (int j = 0; j < 4; ++j)
            pk[j] = cvtpk(tile[kc*8 + 2*j][n_loc], tile[kc*8 + 2*j + 1][n_loc]);
        size_t tidx = (size_t)(n >> 7) * 16 + (kbase >> 6);
        int row = n & 127;
        int byte = (row*128 + (kbase & 63)*2) ^ ((row & 7) << 4);
        *(uint4v*)((char*)wt + tidx*16384 + byte) = pk;
    }
}

// ---------- merged Q/K/V projection GEMM (z = 0/1/2) ----------
// Single-buffered A (av[] registers are the second buffer) + double-buffered B
// via global_load_lds (48KB).  Two uniform barriers per K-step.  2D m-fast
// grid keeps same-m blocks on one XCD.  Epilogues: z=0 Q scaled [b,h,s,64];
// z=1 K sigma-permuted swizzled tile image; z=2 V^T swizzled tile image.
__global__ __launch_bounds__(256) void qkv_gemm_kernel(
        const float* __restrict__ qin, const float* __restrict__ kin,
        const float* __restrict__ vin,
        const unsigned short* __restrict__ wqt, const unsigned short* __restrict__ wkt,
        const unsigned short* __restrict__ wvt,
        const float* __restrict__ bq, const float* __restrict__ bk,
        const float* __restrict__ bv,
        unsigned short* __restrict__ qhd, unsigned short* __restrict__ khd,
        unsigned short* __restrict__ vtd) {
    __shared__ __attribute__((aligned(16))) unsigned short Alds[128*64];
    __shared__ __attribute__((aligned(16))) unsigned short Blds[2][128*64];
    const int z = blockIdx.z;
    const float* Af = (z == 0) ? qin : (z == 1) ? kin : vin;
    const unsigned short* Bt = (z == 0) ? wqt : (z == 1) ? wkt : wvt;
    const float* bias = (z == 0) ? bq : (z == 1) ? bk : bv;
    const int m0 = blockIdx.x * 128;
    const int n0 = blockIdx.y * 128;
    const int t = threadIdx.x;
    const int lane = t & 63;
    const int w = t >> 6;
    const int wm = w >> 1, wn = w & 1;        // 2x2 wave grid, 64x64 each
    const int l15 = lane & 15, lg = lane >> 4;
    const unsigned short* tbase = Bt + (size_t)(n0 >> 7) * 16 * 8192;

    f32x4 acc[4][4];
    #pragma unroll
    for (int i = 0; i < 4; ++i)
        #pragma unroll
        for (int j = 0; j < 4; ++j) acc[i][j] = (f32x4)(0.0f);

    // ---- prologue: stage A(0) (reg convert), issue B(0) ----
    #pragma unroll
    for (int i = 0; i < 8; ++i) {
        int idx = t + i*256;
        int row = idx >> 4, c4 = idx & 15;
        f32x4 v = *(const f32x4*)(Af + (size_t)(m0+row)*D_MODEL + c4*4);
        unsigned long long pk = (unsigned long long)cvtpk(v[0], v[1])
                              | ((unsigned long long)cvtpk(v[2], v[3]) << 32);
        int byte = (row*128 + c4*8) ^ ((row & 7) << 4);
        *(unsigned long long*)((char*)Alds + byte) = pk;
    }
    #pragma unroll
    for (int i = 0; i < 4; ++i)
        gload16(tbase + t*8 + i*2048, Blds[0] + t*8 + i*2048);
    __syncthreads();

    #pragma unroll 2
    for (int kt = 0; kt < 16; ++kt) {
        const int cur = kt & 1, nxt = cur ^ 1;
        f32x4 av[8];
        if (kt < 15) {
            const int k0n = (kt + 1) * 64;
            #pragma unroll
            for (int i = 0; i < 8; ++i) {
                int idx = t + i*256;
                int row = idx >> 4, c4 = idx & 15;
                av[i] = *(const f32x4*)(Af + (size_t)(m0+row)*D_MODEL + k0n + c4*4);
            }
            const unsigned short* tsrc = tbase + (size_t)(kt + 1) * 8192;
            #pragma unroll
            for (int i = 0; i < 4; ++i)
                gload16(tsrc + t*8 + i*2048, Blds[nxt] + t*8 + i*2048);
        }

        #pragma unroll
        for (int kk = 0; kk < 2; ++kk) {
            short8 af[4], bfr[4];
            #pragma unroll
            for (int mi = 0; mi < 4; ++mi) {
                int row = wm*64 + mi*16 + l15;
                int byte = (row*128 + kk*64 + lg*16) ^ ((row & 7) << 4);
                af[mi] = *(const short8*)((const char*)Alds + byte);
            }
            #pragma unroll
            for (int ni = 0; ni < 4; ++ni) {
                int row = wn*64 + ni*16 + l15;
                int byte = (row*128 + kk*64 + lg*16) ^ ((row & 7) << 4);
                bfr[ni] = *(const short8*)((const char*)Blds[cur] + byte);
            }
            #pragma unroll
            for (int mi = 0; mi < 4; ++mi)
                #pragma unroll
                for (int ni = 0; ni < 4; ++ni)
                    acc[mi][ni] = __builtin_amdgcn_mfma_f32_16x16x32_bf16(
                        af[mi], bfr[ni], acc[mi][ni], 0, 0, 0);
        }
        __syncthreads();                       // all waves done reading Alds
        if (kt < 15) {
            #pragma unroll
            for (int i = 0; i < 8; ++i) {
                int idx = t + i*256;
                int row = idx >> 4, c4 = idx & 15;
                unsigned long long pk = (unsigned long long)cvtpk(av[i][0], av[i][1])
                                      | ((unsigned long long)cvtpk(av[i][2], av[i][3]) << 32);
                int byte = (row*128 + c4*8) ^ ((row & 7) << 4);
                *(unsigned long long*)((char*)Alds + byte) = pk;
            }
            __syncthreads();                   // A(kt+1) visible to all waves
        }
    }

    // epilogue: C/D layout col = lane&15, row = (lane>>4)*4 + reg
    #pragma unroll
    for (int mi = 0; mi < 4; ++mi)
        #pragma unroll
        for (int ni = 0; ni < 4; ++ni) {
            int col = n0 + wn*64 + ni*16 + l15;
            float bv_ = bias[col];
            int h = col >> 6, d = col & 63;
            if (z == 0) {
                // Q: bf16 [b,h,s,64], scaled
                #pragma unroll
                for (int r = 0; r < 4; ++r) {
                    int row = m0 + wm*64 + mi*16 + lg*4 + r;
                    int bb = row >> 11, s = row & 2047;
                    float vv = (acc[mi][ni][r] + bv_) * QKSCALE;
                    qhd[(((size_t)(bb*NHEADS + h)*SEQ + s) << 6) + d] = f2bf(vv);
                }
            } else if (z == 1) {
                // K tile image: row=sigma(kv), col=d
                #pragma unroll
                for (int r = 0; r < 4; ++r) {
                    int row = m0 + wm*64 + mi*16 + lg*4 + r;
                    int bb = row >> 11, s = row & 2047;
                    int ti = s >> 6, kvl = s & 63;
                    int ph = (kvl & 0x23) | ((kvl & 4) << 2) | ((kvl & 0x18) >> 1);
                    int byte = (ph*128 + d*2) ^ ((ph & 7) << 4);
                    *(unsigned short*)((char*)khd
                        + ((size_t)(bb*NHEADS + h)*32 + ti)*8192 + byte)
                        = f2bf(acc[mi][ni][r] + bv_);
                }
            } else {
                // V^T tile image: row=d, col=kv; 4 consecutive kv = 8B store
                int row0 = m0 + wm*64 + mi*16 + lg*4;
                int bb = row0 >> 11, s0 = row0 & 2047;
                int ti = s0 >> 6, kvl0 = s0 & 63;
                unsigned long long pk = 0;
                #pragma unroll
                for (int r = 0; r < 4; ++r)
                    pk |= (unsigned long long)f2bf(acc[mi][ni][r] + bv_) << (16*r);
                int byte = (d*128 + kvl0*2) ^ ((d & 7) << 4);
                *(unsigned long long*)((char*)vtd
                    + ((size_t)(bb*NHEADS + h)*32 + ti)*8192 + byte) = pk;
            }
        }
}

// ---------- final GEMM: d_out[8192x1024] f32 = xat * wot^T + bo ----------
__global__ __launch_bounds__(256) void out_gemm_kernel(const unsigned short* __restrict__ Ab,
                                                       const unsigned short* __restrict__ Bt,
                                                       const float* __restrict__ bias,
                                                       float* __restrict__ Out) {
    __shared__ __attribute__((aligned(16))) unsigned short Alds[128*64];
    __shared__ __attribute__((aligned(16))) unsigned short Blds[2][128*64];
    const int m0 = blockIdx.x * 128;
    const int n0 = blockIdx.y * 128;
    const int t = threadIdx.x;
    const int lane = t & 63;
    const int w = t >> 6;
    const int wm = w >> 1, wn = w & 1;
    const int l15 = lane & 15, lg = lane >> 4;
    const unsigned short* tbase = Bt + (size_t)(n0 >> 7) * 16 * 8192;

    f32x4 acc[4][4];
    #pragma unroll
    for (int i = 0; i < 4; ++i)
        #pragma unroll
        for (int j = 0; j < 4; ++j) acc[i][j] = (f32x4)(0.0f);

    // prologue: stage A(0) (reg path), issue B(0)
    #pragma unroll
    for (int i = 0; i < 4; ++i) {
        int idx = t + i*256;
        int row = idx >> 3, c8 = idx & 7;
        short8 v = *(const short8*)(Ab + (size_t)(m0+row)*D_MODEL + c8*8);
        int byte = (row*128 + c8*16) ^ ((row & 7) << 4);
        *(short8*)((char*)Alds + byte) = v;
    }
    #pragma unroll
    for (int i = 0; i < 4; ++i)
        gload16(tbase + t*8 + i*2048, Blds[0] + t*8 + i*2048);
    __syncthreads();

    #pragma unroll 2
    for (int kt = 0; kt < 16; ++kt) {
        const int cur = kt & 1, nxt = cur ^ 1;
        short8 av8[4];
        if (kt < 15) {
            const int k0n = (kt + 1) * 64;
            #pragma unroll
            for (int i = 0; i < 4; ++i) {
                int idx = t + i*256;
                int row = idx >> 3, c8 = idx & 7;
                av8[i] = *(const short8*)(Ab + (size_t)(m0+row)*D_MODEL + k0n + c8*8);
            }
            const unsigned short* tsrc = tbase + (size_t)(kt + 1) * 8192;
            #pragma unroll
            for (int i = 0; i < 4; ++i)
                gload16(tsrc + t*8 + i*2048, Blds[nxt] + t*8 + i*2048);
        }

        #pragma unroll
        for (int kk = 0; kk < 2; ++kk) {
            short8 af[4], bfr[4];
            #pragma unroll
            for (int mi = 0; mi < 4; ++mi) {
                int row = wm*64 + mi*16 + l15;
                int byte = (row*128 + kk*64 + lg*16) ^ ((row & 7) << 4);
                af[mi] = *(const short8*)((const char*)Alds + byte);
            }
            #pragma unroll
            for (int ni = 0; ni < 4; ++ni) {
                int row = wn*64 + ni*16 + l15;
                int byte = (row*128 + kk*64 + lg*16) ^ ((row & 7) << 4);
                bfr[ni] = *(const short8*)((const char*)Blds[cur] + byte);
            }
            #pragma unroll
            for (int mi = 0; mi < 4; ++mi)
                #pragma unroll
                for (int ni = 0; ni < 4; ++ni)
                    acc[mi][ni] = __builtin_amdgcn_mfma_f32_16x16x32_bf16(
                        af[mi], bfr[ni], acc[mi][ni], 0, 0, 0);
        }
        __syncthreads();                       // all waves done reading Alds
        if (kt < 15) {
            #pragma unroll
            for (int i = 0; i < 4; ++i) {
                int idx = t + i*256;
                int row = idx >> 3, c8 = idx & 7;
                int byte = (row*128 + c8*16) ^ ((row & 7) << 4);
                *(short8*)((char*)Alds + byte) = av8[i];
            }
            __syncthreads();                   // A(kt+1) visible
        }
    }

    #pragma unroll
    for (int mi = 0; mi < 4; ++mi)
        #pragma unroll
        for (int ni = 0; ni < 4; ++ni) {
            int col = n0 + wn*64 + ni*16 + l15;
            float bv_ = bias[col];
            #pragma unroll
            for (int r = 0; r < 4; ++r) {
                int row = m0 + wm*64 + mi*16 + lg*4 + r;
                Out[(size_t)row*D_MODEL + col] = acc[mi][ni][r] + bv_;
            }
        }
}

// ---------- flash attention: swapped QK^T, in-register P, 32 q-rows/wave ------
// 4 waves x 32 q-rows = 128 q rows per block; KVBLK=64; double-buffered LDS.
// K/V arrive as pre-swizzled tile images -> staging is pure global_load_lds.
// Softmax: m FIXED at tile-0's row max (one-time tree; defined init).  lsum is
// the per-lane VALU partial, reduced once in the epilogue.
// Grid: flat 1024, bh = (idx&7)*8 + xcd so one head's 16 q-blocks share an XCD.
__global__ __launch_bounds__(256, 4) void attn_kernel(const unsigned short* __restrict__ qh,
                                                      const unsigned short* __restrict__ kimg_all,
                                                      const unsigned short* __restrict__ vimg_all,
                                                      unsigned short* __restrict__ xout) {
    __shared__ __attribute__((aligned(16))) unsigned short Klds[2][64*64];
    __shared__ __attribute__((aligned(16))) unsigned short Vtl[2][64*64];

    const int bid = blockIdx.x;            // 0..1023
    const int xcd = bid & 7, idx = bid >> 3;
    const int qb = idx >> 3;               // 0..15 (128 q rows each)
    const int bh = ((idx & 7) << 3) | xcd; // 0..63; fixed bh -> fixed xcd
    const int t = threadIdx.x;             // 0..255
    const int lane = t & 63;
    const int w = t >> 6;                  // 0..3
    const int l15 = lane & 15, lg = lane >> 4;

    const unsigned short* qbase = qh + (size_t)bh * SEQ * 64;
    const unsigned short* kimg = kimg_all + (size_t)bh * SEQ * 64;
    const unsigned short* vimg = vimg_all + (size_t)bh * SEQ * 64;

    // Q fragments hoisted: wave w owns q rows qb*128 + w*32 + l*16 + l15
    short8 qf[2][2];
    #pragma unroll
    for (int l = 0; l < 2; ++l) {
        int qrow = qb*128 + w*32 + l*16 + l15;
        qf[l][0] = *(const short8*)(qbase + (size_t)qrow*64 + lg*8);
        qf[l][1] = *(const short8*)(qbase + (size_t)qrow*64 + 32 + lg*8);
    }

    // hoisted fragment read offsets (same formula for K and Vt)
    int fb[4][2];
    #pragma unroll
    for (int nb = 0; nb < 4; ++nb) {
        int rr = nb*16 + l15;
        int sw = (rr & 7) << 4;
        fb[nb][0] = (rr*128 + lg*16) ^ sw;
        fb[nb][1] = (rr*128 + 64 + lg*16) ^ sw;
    }

    float m[2] = {-1e30f, -1e30f};   // fixed after tile 0 (per-lane, q = l15)
    float lsum[2] = {0.f, 0.f};      // PER-LANE partial (16-kv slice), q = l15
    f32x4 o[2][4];                   // o[l][nb][r]: q = l*16+lg*4+r, d = nb*16+l15
    #pragma unroll
    for (int l = 0; l < 2; ++l)
        #pragma unroll
        for (int nb = 0; nb < 4; ++nb) o[l][nb] = (f32x4)(0.0f);

    // prologue: stage tile 0 into buffer 0 (pure async DMA)
    #pragma unroll
    for (int i = 0; i < 2; ++i) {
        gload16(kimg + t*8 + i*2048, Klds[0] + t*8 + i*2048);
        gload16(vimg + t*8 + i*2048, Vtl[0] + t*8 + i*2048);
    }
    __syncthreads();

    const unsigned short* kp = kimg + 4096 + t*8;
    const unsigned short* vp = vimg + 4096 + t*8;

    const int NT = SEQ/64;
    #pragma unroll 2
    for (int ti = 0; ti < NT; ++ti) {
        const int c = ti & 1;
        // issue next-tile DMA early (latency hides under compute)
        if (ti + 1 < NT) {
            #pragma unroll
            for (int i = 0; i < 2; ++i) {
                gload16(kp + i*2048, Klds[c^1] + t*8 + i*2048);
                gload16(vp + i*2048, Vtl[c^1] + t*8 + i*2048);
            }
            kp += 4096; vp += 4096;
        }
        const char* Kc = (const char*)Klds[c];
        const char* Vc = (const char*)Vtl[c];

        // S^T = K Q^T for both q-groups, sharing K-fragment reads
        f32x4 s4[2][4];
        #pragma unroll
        for (int nb = 0; nb < 4; ++nb) {
            short8 kf0 = *(const short8*)(Kc + fb[nb][0]);
            short8 kf1 = *(const short8*)(Kc + fb[nb][1]);
            __builtin_amdgcn_s_setprio(1);
            #pragma unroll
            for (int l = 0; l < 2; ++l) {
                f32x4 s = (f32x4)(0.0f);
                s = __builtin_amdgcn_mfma_f32_16x16x32_bf16(kf0, qf[l][0], s, 0, 0, 0);
                s = __builtin_amdgcn_mfma_f32_16x16x32_bf16(kf1, qf[l][1], s, 0, 0, 0);
                s4[l][nb] = s;
            }
            __builtin_amdgcn_s_setprio(0);
        }

        // one-time: m = row max of tile 0 (uniform branch)
        if (ti == 0) {
            #pragma unroll
            for (int l = 0; l < 2; ++l) {
                float tm = s4[l][0][0];
                #pragma unroll
                for (int nb = 0; nb < 4; ++nb)
                    #pragma unroll
                    for (int r = 0; r < 4; ++r) tm = fmaxf(tm, s4[l][nb][r]);
                tm = fmaxf(tm, __shfl_xor(tm, 16));
                tm = fmaxf(tm, __shfl_xor(tm, 32));
                m[l] = tm;
            }
        }

        // softmax: p = 2^(s-m), fixed m; pack PA in-register; lsum per-lane VALU
        union U { short8 s; unsigned int u[4]; } pa[2][2];
        #pragma unroll
        for (int l = 0; l < 2; ++l) {
            float p[16];
            float ts = 0.f;
            #pragma unroll
            for (int nb = 0; nb < 4; ++nb)
                #pragma unroll
                for (int r = 0; r < 4; ++r) {
                    float pv = EXP2(s4[l][nb][r] - m[l]);
                    p[nb*4 + r] = pv;
                    ts += pv;
                }
            lsum[l] += ts;

            // pack PA fragments in-register: pa[l][kk] covers kv = kk*32+lg*8..+7
            pa[l][0].u[0] = cvtpk(p[0],  p[1]);  pa[l][0].u[1] = cvtpk(p[2],  p[3]);
            pa[l][0].u[2] = cvtpk(p[4],  p[5]);  pa[l][0].u[3] = cvtpk(p[6],  p[7]);
            pa[l][1].u[0] = cvtpk(p[8],  p[9]);  pa[l][1].u[1] = cvtpk(p[10], p[11]);
            pa[l][1].u[2] = cvtpk(p[12], p[13]); pa[l][1].u[3] = cvtpk(p[14], p[15]);
        }

        // O += P V, sharing V-fragment reads across both q-groups
        #pragma unroll
        for (int nb = 0; nb < 4; ++nb) {
            short8 vf0 = *(const short8*)(Vc + fb[nb][0]);
            short8 vf1 = *(const short8*)(Vc + fb[nb][1]);
            __builtin_amdgcn_s_setprio(1);
            o[0][nb] = __builtin_amdgcn_mfma_f32_16x16x32_bf16(pa[0][0].s, vf0, o[0][nb], 0, 0, 0);
            o[0][nb] = __builtin_amdgcn_mfma_f32_16x16x32_bf16(pa[0][1].s, vf1, o[0][nb], 0, 0, 0);
            o[1][nb] = __builtin_amdgcn_mfma_f32_16x16x32_bf16(pa[1][0].s, vf0, o[1][nb], 0, 0, 0);
            o[1][nb] = __builtin_amdgcn_mfma_f32_16x16x32_bf16(pa[1][1].s, vf1, o[1][nb], 0, 0, 0);
            __builtin_amdgcn_s_setprio(0);
        }

        __syncthreads();
    }

    // epilogue: reduce lsum partials across lg, then x[b][s][h*64+d] bf16
    const int bb = bh >> 4, h = bh & 15;
    #pragma unroll
    for (int l = 0; l < 2; ++l) {
        float lt = lsum[l];
        lt += __shfl_xor(lt, 16);
        lt += __shfl_xor(lt, 32);
        float rl[4];
        #pragma unroll
        for (int r = 0; r < 4; ++r) rl[r] = 1.0f / __shfl(lt, lg*4 + r);
        #pragma unroll
        for (int nb = 0; nb < 4; ++nb)
            #pragma unroll
            for (int r = 0; r < 4; ++r) {
                int s = qb*128 + w*32 + l*16 + lg*4 + r;
                int d = nb*16 + l15;
                xout[((size_t)(bb*SEQ + s))*D_MODEL + h*64 + d] = f2bf(o[l][nb][r] * rl[r]);
            }
    }
}

extern "C" void kernel_launch(void* const* d_in, const int* in_sizes, int n_in,
                              void* d_out, int out_size, void* d_ws, size_t ws_size,
                              hipStream_t stream) {
    (void)in_sizes; (void)n_in; (void)out_size; (void)ws_size;
    const float* q  = (const float*)d_in[0];
    const float* k  = (const float*)d_in[1];
    const float* v  = (const float*)d_in[2];
    const float* wq = (const float*)d_in[3];
    const float* bq = (const float*)d_in[4];
    const float* wk = (const float*)d_in[5];
    const float* bk = (const float*)d_in[6];
    const float* wv = (const float*)d_in[7];
    const float* bv = (const float*)d_in[8];
    const float* wo = (const float*)d_in[9];
    const float* bo = (const float*)d_in[10];

    // workspace layout (72 MB total)
    char* ws = (char*)d_ws;
    unsigned short* wqt = (unsigned short*)(ws);                    // 2 MB each
    unsigned short* wkt = (unsigned short*)(ws + (2ull << 20));
    unsigned short* wvt = (unsigned short*)(ws + (4ull << 20));
    unsigned short* wot = (unsigned short*)(ws + (6ull << 20));
    unsigned short* qhd = (unsigned short*)(ws + (8ull << 20));     // 16 MB each
    unsigned short* khd = (unsigned short*)(ws + (24ull << 20));
    unsigned short* vtd = (unsigned short*)(ws + (40ull << 20));
    unsigned short* xat = (unsigned short*)(ws + (56ull << 20));

    hipLaunchKernelGGL(wtrans_kernel, dim3(D_MODEL/32, D_MODEL/32, 4), dim3(256), 0, stream,
                       wq, wk, wv, wo, wqt, wkt, wvt, wot);

    hipLaunchKernelGGL(qkv_gemm_kernel, dim3(ROWS/128, D_MODEL/128, 3), dim3(256), 0, stream,
                       q, k, v, wqt, wkt, wvt, bq, bk, bv, qhd, khd, vtd);

    hipLaunchKernelGGL(attn_kernel, dim3(16*64), dim3(256), 0, stream,
                       qhd, khd, vtd, xat);

    hipLaunchKernelGGL(out_gemm_kernel, dim3(ROWS/128, D_MODEL/128), dim3(256), 0, stream,
                       xat, wot, bo, (float*)d_out);
}